// Round 5
// baseline (399.541 us; speedup 1.0000x reference)
//
#include <hip/hip_runtime.h>
#include <math.h>

// x: (32,512,2049) fp32 -> out (32,512,1024) fp32
// segments: n_lin (~631) linear, n_cub (~104) cubic, n_tri (~289) tri-max
#define NI 2049
#define ROWS 4
#define BT 256              // threads per block; block = 256 outputs x ROWS rows
#define WCAP 4096
#define NTRI_MAX 512

// ---------------------------------------------------------------------------
// Pass 1: per tri row, find finite-weight window [start, start+cnt).
// ---------------------------------------------------------------------------
__global__ void logscale_win(const float* __restrict__ w, int n_in,
                             int* __restrict__ tri_start,
                             int* __restrict__ tri_cnt) {
    const int i = blockIdx.x;
    __shared__ int smin, smax;
    if (threadIdx.x == 0) { smin = n_in; smax = -1; }
    __syncthreads();
    int lmin = n_in, lmax = -1;
    const float* wr = w + (size_t)i * n_in;
    for (int b = threadIdx.x; b < n_in; b += blockDim.x) {
        float v = wr[b];
        if (v > -1e30f) { lmin = min(lmin, b); lmax = max(lmax, b); }
    }
    atomicMin(&smin, lmin);
    atomicMax(&smax, lmax);
    __syncthreads();
    if (threadIdx.x == 0) {
        int s = smin, cnt = smax - smin + 1;
        if (cnt < 1) { s = 0; cnt = 1; }
        if (cnt > 64) cnt = 64;          // defensive (real max ~28)
        tri_start[i] = s; tri_cnt[i] = cnt;
    }
}

// ---------------------------------------------------------------------------
// Pass 2 (single block): wave-parallel prefix-sum of tri counts, build fused
// meta[n_out], pack tri weights (one wave per row, coalesced).
// meta per output o:
//   lin : x=i0 y=i1 z=f
//   cub : x=i0      z=f
//   tri : x=start y=cnt z=off(int bits)
// ---------------------------------------------------------------------------
__global__ void logscale_pack(const float* __restrict__ w,
                              const float* __restrict__ flin,
                              const float* __restrict__ fcub,
                              const int*   __restrict__ pidx,
                              const int*   __restrict__ tri_start,
                              const int*   __restrict__ tri_cnt,
                              float4* __restrict__ meta,
                              float*  __restrict__ wpk,
                              int*    __restrict__ d_total,
                              int n_lin, int n_cub, int n_tri) {
    __shared__ int offs[NTRI_MAX + 1];
    __shared__ int starts[NTRI_MAX];
    const int tid = threadIdx.x;
    for (int i = tid; i < n_tri; i += blockDim.x) {
        offs[i + 1] = tri_cnt[i];
        starts[i]   = tri_start[i];
    }
    if (tid == 0) offs[0] = 0;
    __syncthreads();

    // wave-0 parallel scan: 64 lanes x 8 serial each covers NTRI_MAX=512
    if (tid < 64) {
        int v[8];
        int run = 0;
        const int base = tid * 8;
        #pragma unroll
        for (int k = 0; k < 8; ++k) {
            int idx = base + k;
            int c = (idx < n_tri) ? offs[idx + 1] : 0;
            run += c;
            v[k] = run;                       // inclusive within chunk
        }
        int tot = run;
        #pragma unroll
        for (int d = 1; d < 64; d <<= 1) {    // Hillis-Steele across lanes
            int up = __shfl_up(tot, (unsigned)d, 64);
            if (tid >= d) tot += up;
        }
        const int excl = tot - run;           // exclusive carry for this chunk
        #pragma unroll
        for (int k = 0; k < 8; ++k) {
            int idx = base + k;
            if (idx < n_tri) offs[idx + 1] = excl + v[k];
        }
    }
    __syncthreads();
    if (tid == 0) {
        int t = offs[n_tri]; if (t > WCAP) t = WCAP;
        *d_total = t;
    }

    const int n_out = n_lin + n_cub + n_tri;
    for (int o = tid; o < n_out; o += blockDim.x) {
        float4 m;
        if (o < n_lin) {
            m.x = __int_as_float(pidx[o]);
            m.y = __int_as_float(pidx[n_lin + o]);
            m.z = flin[o]; m.w = 0.0f;
        } else if (o < n_lin + n_cub) {
            float c = fcub[o - n_lin];
            int i0 = (int)floorf(c);
            m.x = __int_as_float(i0);
            m.y = 0.0f;
            m.z = c - (float)i0; m.w = 0.0f;
        } else {
            int i = o - n_lin - n_cub;
            int oa = min(offs[i], WCAP), ob = min(offs[i + 1], WCAP);
            m.x = __int_as_float(starts[i]);
            m.y = __int_as_float(ob - oa);
            m.z = __int_as_float(oa); m.w = 0.0f;
        }
        meta[o] = m;
    }

    // weight packing: wave wv handles rows wv, wv+4, ... lanes copy one row
    const int wv = tid >> 6, ln = tid & 63;
    for (int i = wv; i < n_tri; i += 4) {
        const int oa = min(offs[i], WCAP);
        const int ob = min(offs[i + 1], WCAP);
        if (ln < ob - oa)
            wpk[oa + ln] = w[(size_t)i * NI + starts[i] + ln];
    }
}

// ---------------------------------------------------------------------------
// Main: pure global-gather, NO LDS, NO barrier. Three rounds of counters
// showed the bulk-synchronous staging structure leaves all pipes <25% busy
// (barrier drain exposed once per block at only 2 blocks/CU). Instead:
// each thread owns one output x ROWS rows and gathers x directly.
//  - packed weights (16 KB) become L1-resident per CU
//  - adjacent lanes read overlapping x windows -> L1/L2 hits
//  - L3 already absorbs x re-reads (FETCH 66 MB < input 134 MB)
//  - tri inner loop: contiguous loads at compile-time strides -> load
//    immediates, no address VALU; latency hidden by 32 waves/CU TLP.
// blockIdx.x = rt * n_otiles + ot  (o-tiles of one row-tile adjacent).
// ---------------------------------------------------------------------------
__global__ __launch_bounds__(BT) void logscale_main(
    const float*  __restrict__ x,
    const float4* __restrict__ meta,
    const float*  __restrict__ wpk,
    float* __restrict__ out,
    int n_lin, int n_cub, int n_out, int n_rows, int n_otiles) {

    const int ot   = blockIdx.x % n_otiles;
    const int rt   = blockIdx.x / n_otiles;
    const int o    = ot * BT + threadIdx.x;
    const int row0 = rt * ROWS;
    const int rows_here = min(ROWS, n_rows - row0);
    if (o >= n_out) return;

    const float4 m = meta[o];
    const int n_lc = n_lin + n_cub;
    const float* xr = x + (size_t)row0 * NI;
    float* ob = out + (size_t)row0 * n_out + o;

    if (rows_here == ROWS) {
        float res[ROWS];
        if (o < n_lin) {
            const int i0 = __float_as_int(m.x);
            const int i1 = __float_as_int(m.y);
            const float f = m.z;
            #pragma unroll
            for (int r = 0; r < ROWS; ++r) {
                const float x0 = xr[r * NI + i0];
                const float x1 = xr[r * NI + i1];
                res[r] = x0 + f * (x1 - x0);
            }
        } else if (o < n_lc) {
            const int i0 = __float_as_int(m.x);
            const float f = m.z;
            #pragma unroll
            for (int r = 0; r < ROWS; ++r) {
                const float* xp = xr + r * NI + i0;
                const float xm1 = xp[-1];
                const float x0  = xp[0];
                const float x1  = xp[1];
                const float x2  = xp[2];
                res[r] = x0 + 0.5f * f * (x1 - xm1 +
                         f * (2.0f * xm1 - 5.0f * x0 + 4.0f * x1 - x2 +
                         f * (3.0f * (x0 - x1) + x2 - xm1)));
            }
        } else {
            const int s   = __float_as_int(m.x);
            const int cnt = __float_as_int(m.y);
            const int off = __float_as_int(m.z);
            const float* wj = wpk + off;
            const float* xp = xr + s;
            float acc0 = -INFINITY, acc1 = -INFINITY;
            float acc2 = -INFINITY, acc3 = -INFINITY;
            #pragma unroll 4
            for (int j = 0; j < cnt; ++j) {
                const float wv = wj[j];
                acc0 = fmaxf(acc0, xp[j] + wv);
                acc1 = fmaxf(acc1, xp[j + NI] + wv);
                acc2 = fmaxf(acc2, xp[j + 2 * NI] + wv);
                acc3 = fmaxf(acc3, xp[j + 3 * NI] + wv);
            }
            res[0] = acc0; res[1] = acc1; res[2] = acc2; res[3] = acc3;
        }
        #pragma unroll
        for (int r = 0; r < ROWS; ++r)
            ob[(size_t)r * n_out] = res[r];
    } else {
        for (int r = 0; r < rows_here; ++r) {
            const float* xrr = xr + r * NI;
            float res;
            if (o < n_lin) {
                const int i0 = __float_as_int(m.x);
                const int i1 = __float_as_int(m.y);
                const float f = m.z;
                const float x0 = xrr[i0];
                const float x1 = xrr[i1];
                res = x0 + f * (x1 - x0);
            } else if (o < n_lc) {
                const int i0 = __float_as_int(m.x);
                const float f = m.z;
                const float xm1 = xrr[i0 - 1];
                const float x0  = xrr[i0];
                const float x1  = xrr[i0 + 1];
                const float x2  = xrr[i0 + 2];
                res = x0 + 0.5f * f * (x1 - xm1 +
                      f * (2.0f * xm1 - 5.0f * x0 + 4.0f * x1 - x2 +
                      f * (3.0f * (x0 - x1) + x2 - xm1)));
            } else {
                const int s   = __float_as_int(m.x);
                const int cnt = __float_as_int(m.y);
                const int off = __float_as_int(m.z);
                float mx = -INFINITY;
                for (int j = 0; j < cnt; ++j)
                    mx = fmaxf(mx, xrr[s + j] + wpk[off + j]);
                res = mx;
            }
            ob[(size_t)r * n_out] = res;
        }
    }
}

extern "C" void kernel_launch(void* const* d_in, const int* in_sizes, int n_in,
                              void* d_out, int out_size, void* d_ws, size_t ws_size,
                              hipStream_t stream) {
    (void)n_in; (void)ws_size; (void)out_size;
    const float* x    = (const float*)d_in[0];
    const float* flin = (const float*)d_in[1];
    const float* fcub = (const float*)d_in[2];
    const float* w    = (const float*)d_in[3];
    const int*   pidx = (const int*)d_in[4];
    float* out = (float*)d_out;

    const int n_lin  = in_sizes[1];
    const int n_cub  = in_sizes[2];
    const int n_tri  = in_sizes[3] / NI;
    const int n_rows = in_sizes[0] / NI;
    const int n_out  = n_lin + n_cub + n_tri;

    // ws layout: meta[n_out] | wpk[WCAP] | tri_start | tri_cnt | total
    float4* meta      = (float4*)d_ws;
    float*  wpk       = (float*)(meta + n_out);
    int*    tri_start = (int*)(wpk + WCAP);
    int*    tri_cnt   = tri_start + NTRI_MAX;
    int*    d_total   = tri_cnt + NTRI_MAX;

    if (n_tri > 0)
        logscale_win<<<n_tri, 256, 0, stream>>>(w, NI, tri_start, tri_cnt);
    logscale_pack<<<1, 256, 0, stream>>>(w, flin, fcub, pidx, tri_start, tri_cnt,
                                         meta, wpk, d_total, n_lin, n_cub, n_tri);
    const int n_otiles = (n_out + BT - 1) / BT;
    const int n_rtiles = (n_rows + ROWS - 1) / ROWS;
    logscale_main<<<n_rtiles * n_otiles, BT, 0, stream>>>(
        x, meta, wpk, out, n_lin, n_cub, n_out, n_rows, n_otiles);
}

// Round 6
// 263.746 us; speedup vs baseline: 1.5149x; 1.5149x over previous
//
#include <hip/hip_runtime.h>
#include <math.h>

// x: (32,512,2049) fp32 -> out (32,512,1024) fp32
// segments: n_lin (~631) linear, n_cub (~104) cubic, n_tri (~289) tri-max
#define NI 2049
#define ROWS 4
#define BT 512              // threads per block (8 waves)
#define WCAP 4096
#define NTRI_MAX 512

// ---------------------------------------------------------------------------
// Pass 1: per tri row, find finite-weight window [start, start+cnt).
// ---------------------------------------------------------------------------
__global__ void logscale_win(const float* __restrict__ w, int n_in,
                             int* __restrict__ tri_start,
                             int* __restrict__ tri_cnt) {
    const int i = blockIdx.x;
    __shared__ int smin, smax;
    if (threadIdx.x == 0) { smin = n_in; smax = -1; }
    __syncthreads();
    int lmin = n_in, lmax = -1;
    const float* wr = w + (size_t)i * n_in;
    for (int b = threadIdx.x; b < n_in; b += blockDim.x) {
        float v = wr[b];
        if (v > -1e30f) { lmin = min(lmin, b); lmax = max(lmax, b); }
    }
    atomicMin(&smin, lmin);
    atomicMax(&smax, lmax);
    __syncthreads();
    if (threadIdx.x == 0) {
        int s = smin, cnt = smax - smin + 1;
        if (cnt < 1) { s = 0; cnt = 1; }
        if (cnt > 64) cnt = 64;          // defensive (real max ~28)
        tri_start[i] = s; tri_cnt[i] = cnt;
    }
}

// ---------------------------------------------------------------------------
// Pass 2 (single block): wave-parallel prefix-sum of tri counts, build fused
// meta[n_out], pack tri weights (one wave per row, coalesced).
// meta per output o:
//   lin : x=i0 y=i1 z=f
//   cub : x=i0      z=f
//   tri : x=start y=cnt z=off(int bits)
// ---------------------------------------------------------------------------
__global__ void logscale_pack(const float* __restrict__ w,
                              const float* __restrict__ flin,
                              const float* __restrict__ fcub,
                              const int*   __restrict__ pidx,
                              const int*   __restrict__ tri_start,
                              const int*   __restrict__ tri_cnt,
                              float4* __restrict__ meta,
                              float*  __restrict__ wpk,
                              int*    __restrict__ d_total,
                              int n_lin, int n_cub, int n_tri) {
    __shared__ int offs[NTRI_MAX + 1];
    __shared__ int starts[NTRI_MAX];
    const int tid = threadIdx.x;
    for (int i = tid; i < n_tri; i += blockDim.x) {
        offs[i + 1] = tri_cnt[i];
        starts[i]   = tri_start[i];
    }
    if (tid == 0) offs[0] = 0;
    __syncthreads();

    // wave-0 parallel scan: 64 lanes x 8 serial each covers NTRI_MAX=512
    if (tid < 64) {
        int v[8];
        int run = 0;
        const int base = tid * 8;
        #pragma unroll
        for (int k = 0; k < 8; ++k) {
            int idx = base + k;
            int c = (idx < n_tri) ? offs[idx + 1] : 0;
            run += c;
            v[k] = run;                       // inclusive within chunk
        }
        int tot = run;
        #pragma unroll
        for (int d = 1; d < 64; d <<= 1) {    // Hillis-Steele across lanes
            int up = __shfl_up(tot, (unsigned)d, 64);
            if (tid >= d) tot += up;
        }
        const int excl = tot - run;           // exclusive carry for this chunk
        #pragma unroll
        for (int k = 0; k < 8; ++k) {
            int idx = base + k;
            if (idx < n_tri) offs[idx + 1] = excl + v[k];
        }
    }
    __syncthreads();
    if (tid == 0) {
        int t = offs[n_tri]; if (t > WCAP) t = WCAP;
        *d_total = t;
    }

    const int n_out = n_lin + n_cub + n_tri;
    for (int o = tid; o < n_out; o += blockDim.x) {
        float4 m;
        if (o < n_lin) {
            m.x = __int_as_float(pidx[o]);
            m.y = __int_as_float(pidx[n_lin + o]);
            m.z = flin[o]; m.w = 0.0f;
        } else if (o < n_lin + n_cub) {
            float c = fcub[o - n_lin];
            int i0 = (int)floorf(c);
            m.x = __int_as_float(i0);
            m.y = 0.0f;
            m.z = c - (float)i0; m.w = 0.0f;
        } else {
            int i = o - n_lin - n_cub;
            int oa = min(offs[i], WCAP), ob = min(offs[i + 1], WCAP);
            m.x = __int_as_float(starts[i]);
            m.y = __int_as_float(ob - oa);
            m.z = __int_as_float(oa); m.w = 0.0f;
        }
        meta[o] = m;
    }

    // weight packing: wave wv handles rows wv, wv+4, ... lanes copy one row
    const int wv = tid >> 6, ln = tid & 63;
    for (int i = wv; i < n_tri; i += 4) {
        const int oa = min(offs[i], WCAP);
        const int ob = min(offs[i + 1], WCAP);
        if (ln < ob - oa)
            wpk[oa + ln] = w[(size_t)i * NI + starts[i] + ln];
    }
}

// ---------------------------------------------------------------------------
// Per-output compute for a full ROWS tile. x from LDS (fast 5.8-cyc loads —
// round-5 gather experiment proved these are what makes the tri loop fast);
// tri weights from GLOBAL (16 KB packed table, L1-resident — the access
// class that did work in the gather version).
// ---------------------------------------------------------------------------
__device__ __forceinline__ void compute_rows4(
    int o, float4 m, const float* __restrict__ xs, const float* __restrict__ wpk,
    int n_lin, int n_lc, float res[ROWS]) {
    if (o < n_lin) {
        const int i0 = __float_as_int(m.x);
        const int i1 = __float_as_int(m.y);
        const float f = m.z;
        #pragma unroll
        for (int r = 0; r < ROWS; ++r) {
            const int b = r * NI;
            const float x0 = xs[b + i0];
            const float x1 = xs[b + i1];
            res[r] = x0 + f * (x1 - x0);
        }
    } else if (o < n_lc) {
        const int i0 = __float_as_int(m.x);
        const float f = m.z;
        #pragma unroll
        for (int r = 0; r < ROWS; ++r) {
            const int b = r * NI + i0;
            const float xm1 = xs[b - 1];
            const float x0  = xs[b];
            const float x1  = xs[b + 1];
            const float x2  = xs[b + 2];
            res[r] = x0 + 0.5f * f * (x1 - xm1 +
                     f * (2.0f * xm1 - 5.0f * x0 + 4.0f * x1 - x2 +
                     f * (3.0f * (x0 - x1) + x2 - xm1)));
        }
    } else {
        const int s   = __float_as_int(m.x);
        const int cnt = __float_as_int(m.y);
        const int off = __float_as_int(m.z);
        const float* wj = wpk + off;
        const float* xp = xs + s;
        float acc0 = -INFINITY, acc1 = -INFINITY;
        float acc2 = -INFINITY, acc3 = -INFINITY;
        for (int j = 0; j < cnt; ++j) {
            const float wv = wj[j];               // global, L1-resident
            acc0 = fmaxf(acc0, xp[j] + wv);
            acc1 = fmaxf(acc1, xp[j + NI] + wv);
            acc2 = fmaxf(acc2, xp[j + 2 * NI] + wv);
            acc3 = fmaxf(acc3, xp[j + 3 * NI] + wv);
        }
        res[0] = acc0; res[1] = acc1; res[2] = acc2; res[3] = acc3;
    }
}

// ---------------------------------------------------------------------------
// Main: ROWS=4 rows per block, BT=512 (8 waves). LDS = xs only (32.8 KB) ->
// 4 blocks/CU x 8 waves = 32 waves/CU (wave cap) in FOUR independent barrier
// groups (vs round 3's two 16-wave groups): when one block drains its staging
// barrier, three others cover it, and each barrier stages half the bytes.
// Weights come from global (L1). Meta prefetched before the barrier.
// ---------------------------------------------------------------------------
__global__ __launch_bounds__(BT, 8) void logscale_main(
    const float*  __restrict__ x,
    const float4* __restrict__ meta,
    const float*  __restrict__ wpk,
    float* __restrict__ out,
    int n_lin, int n_cub, int n_out, int n_rows) {

    __shared__ __align__(16) float xs[ROWS * NI];   // 8196 floats = 32.8 KB

    const int tid  = threadIdx.x;
    const int row0 = blockIdx.x * ROWS;
    const int rows_here = min(ROWS, n_rows - row0);

    // prefetch metas (issued before staging; consumed after the barrier)
    const int o0 = tid, o1 = tid + BT;
    float4 m0 = make_float4(0.f, 0.f, 0.f, 0.f), m1 = m0;
    if (o0 < n_out) m0 = meta[o0];
    if (o1 < n_out) m1 = meta[o1];

    // float4 staging: tile base byte offset = row0*NI*4 = 32784*blk ≡ 0 mod 16.
    // rows_here==4 -> nx = 8196 floats = 2049 float4 exactly (no tail).
    const float* xr = x + (size_t)row0 * NI;
    const int nx = rows_here * NI;
    const int nq = nx >> 2;
    const float4* xr4 = (const float4*)xr;
    float4* xs4 = (float4*)xs;
    for (int i = tid; i < nq; i += BT) xs4[i] = xr4[i];
    for (int i = (nq << 2) + tid; i < nx; i += BT) xs[i] = xr[i];
    __syncthreads();

    const int n_lc = n_lin + n_cub;
    float* ob = out + (size_t)row0 * n_out;

    if (rows_here == ROWS) {
        float res[ROWS];
        if (o0 < n_out) {
            compute_rows4(o0, m0, xs, wpk, n_lin, n_lc, res);
            #pragma unroll
            for (int r = 0; r < ROWS; ++r) ob[(size_t)r * n_out + o0] = res[r];
        }
        if (o1 < n_out) {
            compute_rows4(o1, m1, xs, wpk, n_lin, n_lc, res);
            #pragma unroll
            for (int r = 0; r < ROWS; ++r) ob[(size_t)r * n_out + o1] = res[r];
        }
        for (int o = tid + 2 * BT; o < n_out; o += BT) {   // generic fallback
            const float4 m = meta[o];
            compute_rows4(o, m, xs, wpk, n_lin, n_lc, res);
            #pragma unroll
            for (int r = 0; r < ROWS; ++r) ob[(size_t)r * n_out + o] = res[r];
        }
    } else {
        for (int o = tid; o < n_out; o += BT) {
            const float4 m = meta[o];
            for (int r = 0; r < rows_here; ++r) {
                const int b = r * NI;
                float res;
                if (o < n_lin) {
                    const int i0 = __float_as_int(m.x);
                    const int i1 = __float_as_int(m.y);
                    const float f = m.z;
                    const float x0 = xs[b + i0];
                    const float x1 = xs[b + i1];
                    res = x0 + f * (x1 - x0);
                } else if (o < n_lc) {
                    const int i0 = __float_as_int(m.x) + b;
                    const float f = m.z;
                    const float xm1 = xs[i0 - 1];
                    const float x0  = xs[i0];
                    const float x1  = xs[i0 + 1];
                    const float x2  = xs[i0 + 2];
                    res = x0 + 0.5f * f * (x1 - xm1 +
                          f * (2.0f * xm1 - 5.0f * x0 + 4.0f * x1 - x2 +
                          f * (3.0f * (x0 - x1) + x2 - xm1)));
                } else {
                    const int s   = __float_as_int(m.x) + b;
                    const int cnt = __float_as_int(m.y);
                    const int off = __float_as_int(m.z);
                    float mx = -INFINITY;
                    for (int j = 0; j < cnt; ++j)
                        mx = fmaxf(mx, xs[s + j] + wpk[off + j]);
                    res = mx;
                }
                ob[(size_t)r * n_out + o] = res;
            }
        }
    }
}

extern "C" void kernel_launch(void* const* d_in, const int* in_sizes, int n_in,
                              void* d_out, int out_size, void* d_ws, size_t ws_size,
                              hipStream_t stream) {
    (void)n_in; (void)ws_size; (void)out_size;
    const float* x    = (const float*)d_in[0];
    const float* flin = (const float*)d_in[1];
    const float* fcub = (const float*)d_in[2];
    const float* w    = (const float*)d_in[3];
    const int*   pidx = (const int*)d_in[4];
    float* out = (float*)d_out;

    const int n_lin  = in_sizes[1];
    const int n_cub  = in_sizes[2];
    const int n_tri  = in_sizes[3] / NI;
    const int n_rows = in_sizes[0] / NI;
    const int n_out  = n_lin + n_cub + n_tri;

    // ws layout: meta[n_out] | wpk[WCAP] | tri_start | tri_cnt | total
    float4* meta      = (float4*)d_ws;
    float*  wpk       = (float*)(meta + n_out);
    int*    tri_start = (int*)(wpk + WCAP);
    int*    tri_cnt   = tri_start + NTRI_MAX;
    int*    d_total   = tri_cnt + NTRI_MAX;

    if (n_tri > 0)
        logscale_win<<<n_tri, 256, 0, stream>>>(w, NI, tri_start, tri_cnt);
    logscale_pack<<<1, 256, 0, stream>>>(w, flin, fcub, pidx, tri_start, tri_cnt,
                                         meta, wpk, d_total, n_lin, n_cub, n_tri);
    const int nblk = (n_rows + ROWS - 1) / ROWS;
    logscale_main<<<nblk, BT, 0, stream>>>(x, meta, wpk, out,
                                           n_lin, n_cub, n_out, n_rows);
}

// Round 7
// 261.773 us; speedup vs baseline: 1.5263x; 1.0075x over previous
//
#include <hip/hip_runtime.h>
#include <math.h>

// x: (32,512,2049) fp32 -> out (32,512,1024) fp32
// segments: n_lin (~631) linear, n_cub (~104) cubic, n_tri (~289) tri-max
#define NI 2049
#define ROWS 4
#define BT 1024             // threads per block (16 waves); n_out==BT -> 1 output/thread
#define WCAP 4096
#define NTRI_MAX 512
#define NBLK 512            // ~2 blocks/CU; each block pipelines ~8 tiles

// ---------------------------------------------------------------------------
// Pass 1: per tri row, find finite-weight window [start, start+cnt).
// ---------------------------------------------------------------------------
__global__ void logscale_win(const float* __restrict__ w, int n_in,
                             int* __restrict__ tri_start,
                             int* __restrict__ tri_cnt) {
    const int i = blockIdx.x;
    __shared__ int smin, smax;
    if (threadIdx.x == 0) { smin = n_in; smax = -1; }
    __syncthreads();
    int lmin = n_in, lmax = -1;
    const float* wr = w + (size_t)i * n_in;
    for (int b = threadIdx.x; b < n_in; b += blockDim.x) {
        float v = wr[b];
        if (v > -1e30f) { lmin = min(lmin, b); lmax = max(lmax, b); }
    }
    atomicMin(&smin, lmin);
    atomicMax(&smax, lmax);
    __syncthreads();
    if (threadIdx.x == 0) {
        int s = smin, cnt = smax - smin + 1;
        if (cnt < 1) { s = 0; cnt = 1; }
        if (cnt > 64) cnt = 64;          // defensive (real max ~28)
        tri_start[i] = s; tri_cnt[i] = cnt;
    }
}

// ---------------------------------------------------------------------------
// Pass 2 (single block): wave-parallel prefix-sum of tri counts, build fused
// meta[n_out], pack tri weights (one wave per row, coalesced).
// meta per output o:
//   lin : x=i0 y=i1 z=f
//   cub : x=i0      z=f
//   tri : x=start y=cnt z=off(int bits)
// ---------------------------------------------------------------------------
__global__ void logscale_pack(const float* __restrict__ w,
                              const float* __restrict__ flin,
                              const float* __restrict__ fcub,
                              const int*   __restrict__ pidx,
                              const int*   __restrict__ tri_start,
                              const int*   __restrict__ tri_cnt,
                              float4* __restrict__ meta,
                              float*  __restrict__ wpk,
                              int*    __restrict__ d_total,
                              int n_lin, int n_cub, int n_tri) {
    __shared__ int offs[NTRI_MAX + 1];
    __shared__ int starts[NTRI_MAX];
    const int tid = threadIdx.x;
    for (int i = tid; i < n_tri; i += blockDim.x) {
        offs[i + 1] = tri_cnt[i];
        starts[i]   = tri_start[i];
    }
    if (tid == 0) offs[0] = 0;
    __syncthreads();

    // wave-0 parallel scan: 64 lanes x 8 serial each covers NTRI_MAX=512
    if (tid < 64) {
        int v[8];
        int run = 0;
        const int base = tid * 8;
        #pragma unroll
        for (int k = 0; k < 8; ++k) {
            int idx = base + k;
            int c = (idx < n_tri) ? offs[idx + 1] : 0;
            run += c;
            v[k] = run;                       // inclusive within chunk
        }
        int tot = run;
        #pragma unroll
        for (int d = 1; d < 64; d <<= 1) {    // Hillis-Steele across lanes
            int up = __shfl_up(tot, (unsigned)d, 64);
            if (tid >= d) tot += up;
        }
        const int excl = tot - run;           // exclusive carry for this chunk
        #pragma unroll
        for (int k = 0; k < 8; ++k) {
            int idx = base + k;
            if (idx < n_tri) offs[idx + 1] = excl + v[k];
        }
    }
    __syncthreads();
    if (tid == 0) {
        int t = offs[n_tri]; if (t > WCAP) t = WCAP;
        *d_total = t;
    }

    const int n_out = n_lin + n_cub + n_tri;
    for (int o = tid; o < n_out; o += blockDim.x) {
        float4 m;
        if (o < n_lin) {
            m.x = __int_as_float(pidx[o]);
            m.y = __int_as_float(pidx[n_lin + o]);
            m.z = flin[o]; m.w = 0.0f;
        } else if (o < n_lin + n_cub) {
            float c = fcub[o - n_lin];
            int i0 = (int)floorf(c);
            m.x = __int_as_float(i0);
            m.y = 0.0f;
            m.z = c - (float)i0; m.w = 0.0f;
        } else {
            int i = o - n_lin - n_cub;
            int oa = min(offs[i], WCAP), ob = min(offs[i + 1], WCAP);
            m.x = __int_as_float(starts[i]);
            m.y = __int_as_float(ob - oa);
            m.z = __int_as_float(oa); m.w = 0.0f;
        }
        meta[o] = m;
    }

    // weight packing: wave wv handles rows wv, wv+4, ... lanes copy one row
    const int wv = tid >> 6, ln = tid & 63;
    for (int i = wv; i < n_tri; i += 4) {
        const int oa = min(offs[i], WCAP);
        const int ob = min(offs[i + 1], WCAP);
        if (ln < ob - oa)
            wpk[oa + ln] = w[(size_t)i * NI + starts[i] + ln];
    }
}

// ---------------------------------------------------------------------------
// Per-output compute for a full ROWS tile. x from LDS (fast throughput
// loads — round-5 gather proved these make the tri loop fast); tri weights
// from GLOBAL (16 KB packed table, L1-resident).
// ---------------------------------------------------------------------------
__device__ __forceinline__ void compute_rows4(
    int o, float4 m, const float* __restrict__ xs, const float* __restrict__ wpk,
    int n_lin, int n_lc, float res[ROWS]) {
    if (o < n_lin) {
        const int i0 = __float_as_int(m.x);
        const int i1 = __float_as_int(m.y);
        const float f = m.z;
        #pragma unroll
        for (int r = 0; r < ROWS; ++r) {
            const int b = r * NI;
            const float x0 = xs[b + i0];
            const float x1 = xs[b + i1];
            res[r] = x0 + f * (x1 - x0);
        }
    } else if (o < n_lc) {
        const int i0 = __float_as_int(m.x);
        const float f = m.z;
        #pragma unroll
        for (int r = 0; r < ROWS; ++r) {
            const int b = r * NI + i0;
            const float xm1 = xs[b - 1];
            const float x0  = xs[b];
            const float x1  = xs[b + 1];
            const float x2  = xs[b + 2];
            res[r] = x0 + 0.5f * f * (x1 - xm1 +
                     f * (2.0f * xm1 - 5.0f * x0 + 4.0f * x1 - x2 +
                     f * (3.0f * (x0 - x1) + x2 - xm1)));
        }
    } else {
        const int s   = __float_as_int(m.x);
        const int cnt = __float_as_int(m.y);
        const int off = __float_as_int(m.z);
        const float* wj = wpk + off;
        const float* xp = xs + s;
        float acc0 = -INFINITY, acc1 = -INFINITY;
        float acc2 = -INFINITY, acc3 = -INFINITY;
        for (int j = 0; j < cnt; ++j) {
            const float wv = wj[j];               // global, L1-resident
            acc0 = fmaxf(acc0, xp[j] + wv);
            acc1 = fmaxf(acc1, xp[j + NI] + wv);
            acc2 = fmaxf(acc2, xp[j + 2 * NI] + wv);
            acc3 = fmaxf(acc3, xp[j + 3 * NI] + wv);
        }
        res[0] = acc0; res[1] = acc1; res[2] = acc2; res[3] = acc3;
    }
}

// ---------------------------------------------------------------------------
// Main: persistent double-buffered pipeline. Six rounds showed the bulk-sync
// structure convoy-stalls (all pipes <25% at any occupancy): blocks stage in
// phase and expose the HBM latency + vmcnt(0) drain once per tile. Here each
// block owns ~8 tiles: issue next tile's global loads into regs -> compute
// current tile from LDS -> write regs to other LDS buffer -> ONE barrier.
// Stage latency is paid once per block, not once per tile. LDS 2x32.8 KB ->
// 2 blocks/CU x 16 waves = 32 waves/CU. meta loaded once per block (each
// thread's output is fixed across tiles). Tile = 8196 floats = 2049 float4
// exactly: v0 covers [0,1024), v1 [1024,2048), v2 elem 2048 (tid 0 only).
// ---------------------------------------------------------------------------
__device__ __forceinline__ void tile_load(const float* __restrict__ x, int t,
                                          int n_rows, int tid,
                                          float4& v0, float4& v1, float4& v2) {
    const float4* xr4 = (const float4*)(x + (size_t)t * (ROWS * NI));
    const int rows_here = min(ROWS, n_rows - t * ROWS);
    if (rows_here == ROWS) {
        v0 = xr4[tid];
        v1 = xr4[tid + BT];
        if (tid == 0) v2 = xr4[2048];
    } else {                                  // partial tile: guarded (rare)
        const int nqp = (rows_here * NI) >> 2;
        if (tid < nqp)      v0 = xr4[tid];
        if (tid + BT < nqp) v1 = xr4[tid + BT];
        if (tid == 0 && 2048 < nqp) v2 = xr4[2048];
    }
}

__device__ __forceinline__ void tile_store(float* __restrict__ xsbuf, int tid,
                                           const float4& v0, const float4& v1,
                                           const float4& v2) {
    float4* xs4 = (float4*)xsbuf;
    xs4[tid]      = v0;
    xs4[tid + BT] = v1;
    if (tid == 0) xs4[2048] = v2;
}

__global__ __launch_bounds__(BT, 8) void logscale_main(
    const float*  __restrict__ x,
    const float4* __restrict__ meta,
    const float*  __restrict__ wpk,
    float* __restrict__ out,
    int n_lin, int n_cub, int n_out, int n_rows, int n_tiles) {

    __shared__ __align__(16) float xs[2][ROWS * NI];   // 2 x 32.8 KB

    const int tid  = threadIdx.x;
    const int n_lc = n_lin + n_cub;

    int t = blockIdx.x;
    if (t >= n_tiles) return;                 // uniform whole-block exit

    // meta: fixed per thread across all tiles of this block
    float4 m0 = make_float4(0.f, 0.f, 0.f, 0.f);
    if (tid < n_out) m0 = meta[tid];

    // prologue: stage first tile (only full-latency exposure for this block)
    float4 v0 = make_float4(0.f,0.f,0.f,0.f), v1 = v0, v2 = v0;
    tile_load(x, t, n_rows, tid, v0, v1, v2);
    tile_store(xs[0], tid, v0, v1, v2);
    __syncthreads();

    int cur = 0;
    while (true) {
        const int tn = t + gridDim.x;
        const bool have_next = tn < n_tiles;
        if (have_next) tile_load(x, tn, n_rows, tid, v0, v1, v2);  // in flight

        // ---- compute tile t from xs[cur] ----
        const int row0 = t * ROWS;
        const int rows_here = min(ROWS, n_rows - row0);
        float* ob = out + (size_t)row0 * n_out;
        const float* xsc = xs[cur];

        if (rows_here == ROWS) {
            float res[ROWS];
            if (tid < n_out) {
                compute_rows4(tid, m0, xsc, wpk, n_lin, n_lc, res);
                #pragma unroll
                for (int r = 0; r < ROWS; ++r)
                    ob[(size_t)r * n_out + tid] = res[r];
            }
            for (int o = tid + BT; o < n_out; o += BT) {   // n_out > BT fallback
                const float4 m = meta[o];
                compute_rows4(o, m, xsc, wpk, n_lin, n_lc, res);
                #pragma unroll
                for (int r = 0; r < ROWS; ++r)
                    ob[(size_t)r * n_out + o] = res[r];
            }
        } else {
            // partial tile (rare): compute straight from global, LDS unused
            for (int o = tid; o < n_out; o += BT) {
                const float4 m = (o == tid) ? m0 : meta[o];
                for (int r = 0; r < rows_here; ++r) {
                    const float* xrr = x + (size_t)(row0 + r) * NI;
                    float res;
                    if (o < n_lin) {
                        const int i0 = __float_as_int(m.x);
                        const int i1 = __float_as_int(m.y);
                        const float f = m.z;
                        const float x0 = xrr[i0];
                        const float x1 = xrr[i1];
                        res = x0 + f * (x1 - x0);
                    } else if (o < n_lc) {
                        const int i0 = __float_as_int(m.x);
                        const float f = m.z;
                        const float xm1 = xrr[i0 - 1];
                        const float x0  = xrr[i0];
                        const float x1  = xrr[i0 + 1];
                        const float x2  = xrr[i0 + 2];
                        res = x0 + 0.5f * f * (x1 - xm1 +
                              f * (2.0f * xm1 - 5.0f * x0 + 4.0f * x1 - x2 +
                              f * (3.0f * (x0 - x1) + x2 - xm1)));
                    } else {
                        const int s   = __float_as_int(m.x);
                        const int cnt = __float_as_int(m.y);
                        const int off = __float_as_int(m.z);
                        float mx = -INFINITY;
                        for (int j = 0; j < cnt; ++j)
                            mx = fmaxf(mx, xrr[s + j] + wpk[off + j]);
                        res = mx;
                    }
                    ob[(size_t)r * n_out + o] = res;
                }
            }
        }

        if (!have_next) break;
        // write next tile into the other buffer. Safe without a pre-barrier:
        // xs[cur^1] was last read in compute(t-1), separated by the previous
        // iteration's __syncthreads. vmcnt wait for v0..v2 lands here, fully
        // hidden under the compute above.
        tile_store(xs[cur ^ 1], tid, v0, v1, v2);
        __syncthreads();                      // xs[cur^1] visible to all
        cur ^= 1;
        t = tn;
    }
}

extern "C" void kernel_launch(void* const* d_in, const int* in_sizes, int n_in,
                              void* d_out, int out_size, void* d_ws, size_t ws_size,
                              hipStream_t stream) {
    (void)n_in; (void)ws_size; (void)out_size;
    const float* x    = (const float*)d_in[0];
    const float* flin = (const float*)d_in[1];
    const float* fcub = (const float*)d_in[2];
    const float* w    = (const float*)d_in[3];
    const int*   pidx = (const int*)d_in[4];
    float* out = (float*)d_out;

    const int n_lin  = in_sizes[1];
    const int n_cub  = in_sizes[2];
    const int n_tri  = in_sizes[3] / NI;
    const int n_rows = in_sizes[0] / NI;
    const int n_out  = n_lin + n_cub + n_tri;

    // ws layout: meta[n_out] | wpk[WCAP] | tri_start | tri_cnt | total
    float4* meta      = (float4*)d_ws;
    float*  wpk       = (float*)(meta + n_out);
    int*    tri_start = (int*)(wpk + WCAP);
    int*    tri_cnt   = tri_start + NTRI_MAX;
    int*    d_total   = tri_cnt + NTRI_MAX;

    if (n_tri > 0)
        logscale_win<<<n_tri, 256, 0, stream>>>(w, NI, tri_start, tri_cnt);
    logscale_pack<<<1, 256, 0, stream>>>(w, flin, fcub, pidx, tri_start, tri_cnt,
                                         meta, wpk, d_total, n_lin, n_cub, n_tri);
    const int n_tiles = (n_rows + ROWS - 1) / ROWS;
    const int nblk = min(NBLK, n_tiles);
    logscale_main<<<nblk, BT, 0, stream>>>(x, meta, wpk, out,
                                           n_lin, n_cub, n_out, n_rows, n_tiles);
}

// Round 9
// 260.996 us; speedup vs baseline: 1.5308x; 1.0030x over previous
//
#include <hip/hip_runtime.h>
#include <math.h>

// x: (32,512,2049) fp32 -> out (32,512,1024) fp32
// segments: n_lin (~631) linear, n_cub (~104) cubic, n_tri (~289) tri-max
#define NI 2049
#define RA 8                // rows per thread, lin/cub kernel
#define RB 4                // rows per tile, tri kernel
#define BBT 512             // threads per block, tri kernel (8 waves)
#define WSTRIDE 32          // fixed wpk row stride (real max window ~28)

// ---------------------------------------------------------------------------
// Pass 1: per tri row, find finite-weight window [start, start+cnt) AND
// copy the window into wpk at fixed stride (absorbs the old pack kernel —
// fixed stride needs no prefix sum, so the serial single-block pack and its
// launch latency are eliminated).
// ---------------------------------------------------------------------------
__global__ void logscale_win(const float* __restrict__ w, int n_in,
                             int* __restrict__ tri_start,
                             int* __restrict__ tri_cnt,
                             float* __restrict__ wpk) {
    const int i = blockIdx.x;
    __shared__ int smin, smax, ss, scnt;
    if (threadIdx.x == 0) { smin = n_in; smax = -1; }
    __syncthreads();
    int lmin = n_in, lmax = -1;
    const float* wr = w + (size_t)i * n_in;
    for (int b = threadIdx.x; b < n_in; b += blockDim.x) {
        float v = wr[b];
        if (v > -1e30f) { lmin = min(lmin, b); lmax = max(lmax, b); }
    }
    atomicMin(&smin, lmin);
    atomicMax(&smax, lmax);
    __syncthreads();
    if (threadIdx.x == 0) {
        int s = smin, cnt = smax - smin + 1;
        if (cnt < 1) { s = 0; cnt = 1; }
        if (cnt > WSTRIDE) cnt = WSTRIDE;   // defensive (real max ~28)
        tri_start[i] = s; tri_cnt[i] = cnt;
        ss = s; scnt = cnt;
    }
    __syncthreads();
    const int s = ss, cnt = scnt;
    for (int j = threadIdx.x; j < cnt; j += blockDim.x)
        wpk[i * WSTRIDE + j] = wr[s + j];
}

// ---------------------------------------------------------------------------
// Kernel A: lin + cub outputs. Pure streaming gather — no LDS, no barrier.
// Per thread: one output x RA rows. lin = 2 loads/row at nearly-consecutive
// per-lane addresses (linear-region index step is 0/1 -> coalesced, L2/L3
// hot); cub = 4 contiguous loads/row. 8-16 independent loads/thread of ILP +
// full occupancy (no LDS, low VGPR) hides latency. Meta read inline from
// pidx/flin/fcub (L1-hot, replaces the meta table).
// ---------------------------------------------------------------------------
__global__ __launch_bounds__(256) void logscale_lincub(
    const float* __restrict__ x,
    const float* __restrict__ flin,
    const float* __restrict__ fcub,
    const int*   __restrict__ pidx,
    float* __restrict__ out,
    int n_lin, int n_lc, int n_out, int n_rows, int n_ochunks) {

    const int ot   = blockIdx.x % n_ochunks;
    const int rt   = blockIdx.x / n_ochunks;
    const int o    = ot * 256 + threadIdx.x;
    const int row0 = rt * RA;
    if (o >= n_lc) return;
    const int rows_here = min(RA, n_rows - row0);

    const float* xr = x + (size_t)row0 * NI;
    float* ob = out + (size_t)row0 * n_out + o;

    if (o < n_lin) {
        const int i0 = pidx[o];
        const int i1 = pidx[n_lin + o];
        const float f = flin[o];
        if (rows_here == RA) {
            float x0[RA], x1[RA];
            #pragma unroll
            for (int r = 0; r < RA; ++r) {
                x0[r] = xr[(size_t)r * NI + i0];
                x1[r] = xr[(size_t)r * NI + i1];
            }
            #pragma unroll
            for (int r = 0; r < RA; ++r)
                ob[(size_t)r * n_out] = x0[r] + f * (x1[r] - x0[r]);
        } else {
            for (int r = 0; r < rows_here; ++r) {
                const float x0 = xr[(size_t)r * NI + i0];
                const float x1 = xr[(size_t)r * NI + i1];
                ob[(size_t)r * n_out] = x0 + f * (x1 - x0);
            }
        }
    } else {
        const float c = fcub[o - n_lin];
        const int i0 = (int)floorf(c);
        const float f = c - (float)i0;
        if (rows_here == RA) {
            float res[RA];
            #pragma unroll
            for (int r = 0; r < RA; ++r) {
                const float* xp = xr + (size_t)r * NI + i0;
                const float xm1 = xp[-1];
                const float x0  = xp[0];
                const float x1  = xp[1];
                const float x2  = xp[2];
                res[r] = x0 + 0.5f * f * (x1 - xm1 +
                         f * (2.0f * xm1 - 5.0f * x0 + 4.0f * x1 - x2 +
                         f * (3.0f * (x0 - x1) + x2 - xm1)));
            }
            #pragma unroll
            for (int r = 0; r < RA; ++r)
                ob[(size_t)r * n_out] = res[r];
        } else {
            for (int r = 0; r < rows_here; ++r) {
                const float* xp = xr + (size_t)r * NI + i0;
                const float xm1 = xp[-1];
                const float x0  = xp[0];
                const float x1  = xp[1];
                const float x2  = xp[2];
                ob[(size_t)r * n_out] = x0 + 0.5f * f * (x1 - xm1 +
                    f * (2.0f * xm1 - 5.0f * x0 + 4.0f * x1 - x2 +
                    f * (3.0f * (x0 - x1) + x2 - xm1)));
            }
        }
    }
}

// ---------------------------------------------------------------------------
// Kernel B: tri outputs only. LDS x-staging kept (round-5 gather proved the
// tri inner loop needs fast x reads), but tri work is spread across ALL
// waves at (output,row)-task granularity: 289x4 = 1156 tasks over 512
// threads, heavy outputs (largest cnt, at high oi) assigned first so the
// final short pass carries the cheapest outputs. Worst thread ~38 inner
// iterations vs 112 in the fused kernel's tri wave; no lin waves idling
// behind it. Weights from global wpk (fixed stride, 4 lanes/output
// broadcast, L1-hot); per-task window meta from tri_start/cnt (L1-hot).
// LDS 32.8 KB -> 4 blocks/CU x 8 waves = 32 waves/CU.
// ---------------------------------------------------------------------------
__global__ __launch_bounds__(BBT, 8) void logscale_tri(
    const float* __restrict__ x,
    const float* __restrict__ wpk,
    const int*   __restrict__ tri_start,
    const int*   __restrict__ tri_cnt,
    float* __restrict__ out,
    int n_lc, int n_out, int n_rows, int n_tri) {

    __shared__ __align__(16) float xs[RB * NI];   // 8196 floats = 32.8 KB

    const int tid  = threadIdx.x;
    const int row0 = blockIdx.x * RB;
    const int rows_here = min(RB, n_rows - row0);

    // float4 staging (tile base = 32784*blk bytes, 16B-aligned; full tile =
    // 2049 float4 exactly).
    const float* xr = x + (size_t)row0 * NI;
    const int nx = rows_here * NI;
    const int nq = nx >> 2;
    const float4* xr4 = (const float4*)xr;
    float4* xs4 = (float4*)xs;
    for (int i = tid; i < nq; i += BBT) xs4[i] = xr4[i];
    for (int i = (nq << 2) + tid; i < nx; i += BBT) xs[i] = xr[i];
    __syncthreads();

    const int ntask = n_tri * RB;
    for (int t = tid; t < ntask; t += BBT) {
        const int oi = (n_tri - 1) - (t >> 2);    // heavy-first (cnt grows with oi)
        const int r  = t & 3;                     // RB == 4
        if (r >= rows_here) continue;
        const int s   = tri_start[oi];
        const int cnt = tri_cnt[oi];
        const float* wj = wpk + oi * WSTRIDE;
        const float* xp = xs + r * NI + s;
        float mx = -INFINITY;
        for (int j = 0; j < cnt; ++j)
            mx = fmaxf(mx, xp[j] + wj[j]);
        out[(size_t)(row0 + r) * n_out + (n_lc + oi)] = mx;
    }
}

extern "C" void kernel_launch(void* const* d_in, const int* in_sizes, int n_in,
                              void* d_out, int out_size, void* d_ws, size_t ws_size,
                              hipStream_t stream) {
    (void)n_in; (void)ws_size; (void)out_size;
    const float* x    = (const float*)d_in[0];
    const float* flin = (const float*)d_in[1];
    const float* fcub = (const float*)d_in[2];
    const float* w    = (const float*)d_in[3];
    const int*   pidx = (const int*)d_in[4];
    float* out = (float*)d_out;

    const int n_lin  = in_sizes[1];
    const int n_cub  = in_sizes[2];
    const int n_tri  = in_sizes[3] / NI;
    const int n_rows = in_sizes[0] / NI;
    const int n_out  = n_lin + n_cub + n_tri;
    const int n_lc   = n_lin + n_cub;

    // ws layout (sized by actual n_tri, ~39 KB total — same class as all
    // passing rounds): wpk[n_tri*WSTRIDE] | tri_start[n_tri] | tri_cnt[n_tri]
    float* wpk        = (float*)d_ws;
    int*   tri_start  = (int*)(wpk + (size_t)n_tri * WSTRIDE);
    int*   tri_cnt    = tri_start + n_tri;

    if (n_tri > 0)
        logscale_win<<<n_tri, 256, 0, stream>>>(w, NI, tri_start, tri_cnt, wpk);

    if (n_lc > 0) {
        const int n_ochunks = (n_lc + 255) / 256;
        const int n_rtA = (n_rows + RA - 1) / RA;
        logscale_lincub<<<n_rtA * n_ochunks, 256, 0, stream>>>(
            x, flin, fcub, pidx, out, n_lin, n_lc, n_out, n_rows, n_ochunks);
    }

    if (n_tri > 0) {
        const int n_rtB = (n_rows + RB - 1) / RB;
        logscale_tri<<<n_rtB, BBT, 0, stream>>>(
            x, wpk, tri_start, tri_cnt, out, n_lc, n_out, n_rows, n_tri);
    }
}